// Round 9
// baseline (132.116 us; speedup 1.0000x reference)
//
#include <hip/hip_runtime.h>
#include <stdint.h>

#define IH 4096
#define IW 4096
#define OH 4090
#define OW 4090

#define TW 256            // output cols per block
#define NW 4              // waves per block
#define RPW 32            // output rows per wave strip
#define RSTEP 4           // output rows per step
#define NSTEP 8           // steps per strip (RPW/RSTEP)
#define WIN 10            // input rows read per step (RSTEP+6)
#define RING 14           // wave-private ring rows = WIN + RSTEP prefetch
#define LW 272            // floats per LDS row
#define YB (NW * RPW)     // 128 rows per block

typedef float v2f __attribute__((ext_vector_type(2)));
typedef __attribute__((address_space(1))) void gas_void;
typedef __attribute__((address_space(3))) void las_void;

// R8 (measured, 48.6us = R7): doubling waves/SIMD changed NOTHING -> not
// latency-starved. Floors: FMA 10.5us, LDS pipe ~10us (the 16.9/b128
// "conflicts" are the inherent free 2-lane/bank aliasing of wave64 b128 --
// constant per-instr across all rounds = artifact), HBM 17us. Fit across
// R6/R7/R8: duration ~= HBM + LDS + VALU ADDED -- the per-step block-wide
// barrier+drain convoys all waves into the same phase; pipes serialize.
// R9: ZERO barriers. Wave-private 14-row ring (15.2KB) + private 32-row
// strip; only sync = per-wave counted vmcnt on its OWN stage loads. Waves
// free-run -> staging/compute/stores overlap across 8 waves/CU.
// Exact ledger via inline-asm stores (no merge/reorder): per step 8 stage
// loads then 8 stores -> vmcnt(16) retires stage(s) exactly (floats
// stores(s-1) + stage(s+1)); vmcnt(8) at s=0 (no prior stores) and s=7
// (no next stage). Ring: reads (4s..4s+9)%14, writes (4s+10..13)%14,
// disjoint; next step's reads fenced by its own vmcnt.
// Halo: 38 staged rows / 32 output rows = 1.19x logical reads, L2/L3-absorbed.

__device__ __forceinline__ void stage_row(const float* __restrict__ x,
                                          int iy, int slot, int tile_x0,
                                          float* ring, int tx)
{
    iy = iy < IH ? iy : IH - 1;                       // safety clamp (never consumed)
    const float* gr = x + ((size_t)iy << 12);
    // Chunk 1: 64 lanes x 16B -> ring cols 0..255 <- x[tile_x0..tile_x0+255].
    // tile_x0 <= 3834 -> c0 <= 4086 <= IW-4: in-bounds, exact mapping.
    const int c0 = tile_x0 + 4 * tx;
    float* lp = ring + slot * LW;                     // wave-uniform LDS base
    __builtin_amdgcn_global_load_lds((gas_void*)(gr + c0), (las_void*)lp, 16, 0, 0);
    // Chunk 2: 16 lanes x 4B -> cols 256..271, per-float clamp (exact mapping
    // for every consumed col; max consumed 261 = x col 4095 on edge tile).
    int c1 = tile_x0 + 256 + tx;
    c1 = c1 <= IW - 1 ? c1 : IW - 1;
    if (tx < 16)                                      // lanes 0..15 active -> 1 instr always issued
        __builtin_amdgcn_global_load_lds((gas_void*)(gr + c1), (las_void*)(lp + 256), 4, 0, 0);
}

__global__ __launch_bounds__(256, 2) void conv7x7_wavering(
    const float* __restrict__ x,
    const float* __restrict__ w,
    const float* __restrict__ bias,
    float* __restrict__ out)
{
    __shared__ float smem[NW * RING * LW];            // 60,928 B -> 2 blocks/CU

    const int tid = threadIdx.x;
    const int tx  = tid & 63;
    const int wv  = tid >> 6;                         // 0..3

    // Shift-clamped tile origins (edge overlap recomputed; benign identical
    // double-stores) -> guard-free epilogue, exact uniform vmem counts.
    int tile_x0 = blockIdx.x * TW;
    if (tile_x0 > OW - TW) tile_x0 = OW - TW;         // 3834 (even -> 8B store align)
    int y0 = blockIdx.y * YB;
    if (y0 > OH - YB) y0 = OH - YB;                   // 3962

    const int strip_y0 = y0 + RPW * wv;               // wave-private strip
    float* ring = smem + wv * (RING * LW);            // wave-private ring

    // Wave-uniform weights -> SGPRs.
    float wt[49];
#pragma unroll
    for (int k = 0; k < 49; ++k) wt[k] = w[k];
    const float b = bias[0];

    // Prologue: stage strip rows 0..9 into slots 0..9 (20 vmem).
#pragma unroll
    for (int r = 0; r < WIN; ++r)
        stage_row(x, strip_y0 + r, r, tile_x0, ring, tx);

    const int lx0 = 4 * tx;
    const int ox0 = tile_x0 + lx0;
    int base = 0;                                     // = (RSTEP*s) % RING

#pragma unroll 1
    for (int s = 0; s < NSTEP; ++s) {
        // Stage next step's 4 NEW rows (8 vmem) into slots (base+10..13)%14.
        if (s + 1 < NSTEP) {
#pragma unroll
            for (int j = 0; j < RSTEP; ++j) {
                int sl = base + WIN + j;              // <= 13+13 = 26
                if (sl >= RING) sl -= RING;
                stage_row(x, strip_y0 + RSTEP * s + WIN + j, sl, tile_x0, ring, tx);
            }
        }
        __builtin_amdgcn_sched_barrier(0);            // pin stage issue above the wait

        // Private counted wait: retire stage(s), float everything newer.
        // s=0: outstanding = prologue(20)+stage1(8) -> vmcnt(8) retires prologue.
        // 1<=s<=6: newer-than-stage(s) = stores(s-1)(8)+stage(s+1)(8) = 16.
        // s=7: newer-than-stage(7) = stores(6)(8) -> vmcnt(8).
        if (s == 0 || s == NSTEP - 1) {
            asm volatile("s_waitcnt vmcnt(8)" ::: "memory");
        } else {
            asm volatile("s_waitcnt vmcnt(16)" ::: "memory");
        }
        __builtin_amdgcn_sched_barrier(0);            // no ds_read hoist above the wait

        float acc[RSTEP][4];
#pragma unroll
        for (int r = 0; r < RSTEP; ++r)
#pragma unroll
            for (int c = 0; c < 4; ++c) acc[r][c] = b;

#pragma unroll
        for (int ir = 0; ir < WIN; ++ir) {            // 10 input rows per 4-row band
            int sl = base + ir;                       // <= 13+9 = 22 -> one wrap
            if (sl >= RING) sl -= RING;
            const float* srow = ring + sl * LW + lx0;
            const float4 q0 = *(const float4*)(srow);       // b128, 16B lane stride
            const float4 q1 = *(const float4*)(srow + 4);
            const float4 q2 = *(const float4*)(srow + 8);   // floats 8,9 used
            float rb[12];
            rb[0]=q0.x; rb[1]=q0.y; rb[2]=q0.z;  rb[3]=q0.w;
            rb[4]=q1.x; rb[5]=q1.y; rb[6]=q1.z;  rb[7]=q1.w;
            rb[8]=q2.x; rb[9]=q2.y; rb[10]=q2.z; rb[11]=q2.w;

#pragma unroll
            for (int ky = 0; ky < 7; ++ky) {
                const int ry = ir - ky;               // compile-time folded
                if (ry >= 0 && ry < RSTEP) {
#pragma unroll
                    for (int kx = 0; kx < 7; ++kx) {
                        const float ww = wt[ky * 7 + kx];   // SGPR operand
#pragma unroll
                        for (int c = 0; c < 4; ++c)
                            acc[ry][c] += ww * rb[kx + c];  // v_fmac v,s,v
                    }
                }
            }
        }

        // Stores: exactly 8 inline-asm dwordx2 per wave per step (compiler
        // cannot merge/reorder -> vmcnt ledger exact). Temporal: combine in
        // L2 write-allocate (R3 lesson: nt stores in flight never combine).
#pragma unroll
        for (int ry = 0; ry < RSTEP; ++ry) {
            const int oy = strip_y0 + RSTEP * s + ry;
            float* orow = out + (size_t)oy * OW + ox0;
            v2f v0 = { acc[ry][0], acc[ry][1] };
            v2f v1 = { acc[ry][2], acc[ry][3] };
            asm volatile("global_store_dwordx2 %0, %1, off"
                         :: "v"(orow), "v"(v0));
            asm volatile("global_store_dwordx2 %0, %1, off"
                         :: "v"(orow + 2), "v"(v1));
        }

        base += RSTEP;
        if (base >= RING) base -= RING;
    }
}

extern "C" void kernel_launch(void* const* d_in, const int* in_sizes, int n_in,
                              void* d_out, int out_size, void* d_ws, size_t ws_size,
                              hipStream_t stream) {
    const float* x    = (const float*)d_in[0];
    const float* w    = (const float*)d_in[1];
    const float* bias = (const float*)d_in[2];
    float* out        = (float*)d_out;

    // 16 x-tiles x 32 y-tiles = 512 blocks = exactly 2/CU (60.9KB LDS),
    // 8 free-running waves/CU, zero barriers, single round, no tail.
    dim3 grid((OW + TW - 1) / TW, 4096 / YB);
    conv7x7_wavering<<<grid, dim3(256), 0, stream>>>(x, w, bias, out);
}